// Round 13
// baseline (221.948 us; speedup 1.0000x reference)
//
#include <hip/hip_runtime.h>
#include <math.h>

// Problem constants (fixed by reference setup_inputs)
constexpr int B = 2, C = 16, H = 160, W = 192, S = 3, D = 48;
constexpr int HW = H * W;          // 30720 = 120 * 256
constexpr int SB = S * B;

// 8-byte vector load with only 4-byte alignment guarantee (pair base is
// an arbitrary pixel). gfx9+ global memory supports unaligned access;
// backend emits a single global_load_dwordx2. Worst case it splits into
// 2 dwords = exactly the old load count (neutral).
typedef float v2f __attribute__((ext_vector_type(2), aligned(4)));

// ------------------------------------------------------------------
// Setup kernel: per (s,b) fold projection chain into
//   A = Ks * R * inv(Kref) (3x3 f64), q = Ks * t (f64)
// so main kernel does p = depth*(A*[u,v,1]) + q.
// ws layout: (s*B+b)*12 doubles = [A row-major 0..8][q 9..11]
// ------------------------------------------------------------------
__global__ void precompute_mats(const float* __restrict__ ref_intr,
                                const float* __restrict__ src_intr,
                                const float* __restrict__ ref_to_src,
                                double* __restrict__ ws)
{
    const int i = threadIdx.x;
    if (i >= SB) return;
    const int b = i % B;

    const float* Kp = ref_intr + b * 9;
    const double a00 = Kp[0], a01 = Kp[1], a02 = Kp[2];
    const double a10 = Kp[3], a11 = Kp[4], a12 = Kp[5];
    const double a20 = Kp[6], a21 = Kp[7], a22 = Kp[8];
    const double c00 =  (a11 * a22 - a12 * a21);
    const double c01 = -(a10 * a22 - a12 * a20);
    const double c02 =  (a10 * a21 - a11 * a20);
    const double c10 = -(a01 * a22 - a02 * a21);
    const double c11 =  (a00 * a22 - a02 * a20);
    const double c12 = -(a00 * a21 - a01 * a20);
    const double c20 =  (a01 * a12 - a02 * a11);
    const double c21 = -(a00 * a12 - a02 * a10);
    const double c22 =  (a00 * a11 - a01 * a10);
    const double invdet = 1.0 / (a00 * c00 + a01 * c01 + a02 * c02);
    const double iK[9] = { c00 * invdet, c10 * invdet, c20 * invdet,
                           c01 * invdet, c11 * invdet, c21 * invdet,
                           c02 * invdet, c12 * invdet, c22 * invdet };

    const float* Tp = ref_to_src + i * 16;
    const float* Ks = src_intr + i * 9;

    double M[9];  // R * inv(K)
    #pragma unroll
    for (int r = 0; r < 3; ++r)
        #pragma unroll
        for (int c = 0; c < 3; ++c)
            M[r * 3 + c] = (double)Tp[r * 4 + 0] * iK[0 + c]
                         + (double)Tp[r * 4 + 1] * iK[3 + c]
                         + (double)Tp[r * 4 + 2] * iK[6 + c];

    double* o = ws + i * 12;
    #pragma unroll
    for (int r = 0; r < 3; ++r) {
        #pragma unroll
        for (int c = 0; c < 3; ++c)
            o[r * 3 + c] = (double)Ks[r * 3 + 0] * M[0 + c]
                         + (double)Ks[r * 3 + 1] * M[3 + c]
                         + (double)Ks[r * 3 + 2] * M[6 + c];
        o[9 + r] = (double)Ks[r * 3 + 0] * (double)Tp[3]
                 + (double)Ks[r * 3 + 1] * (double)Tp[7]
                 + (double)Ks[r * 3 + 2] * (double)Tp[11];
    }
}

// ------------------------------------------------------------------
// Main kernel. 2D grid (R4): blockIdx.y = b*D+d -> b/d/s wave-uniform,
// channel bases scalarize (saddr loads, SALU walks). NCHW stride-1
// coalesced (R3 lesson). NO min-waves __launch_bounds__ (R2/R5 HARD
// RULE: forced caps -> catastrophic scratch spills). FULL unroll of
// the channel loop (R10/R12 lesson: partial unroll serializes chunk
// vmcnt drains -> 63% busy; the contiguous load-issue window is the
// controlling variable). ND=1 (R7/R8/R10: sharing never beat R6/R11).
//
// Round-13: halve VMEM instructions at IDENTICAL loop structure.
// Bilinear taps are x-adjacent pairs -> one dwordx2 per row instead
// of two dwords: 256 -> 112 loads/thread. Pair base clamped to
// xp = clamp(x0,0,W-2) (never OOB); weights remapped onto pair lanes
// once per source (interior: (w00,w01); x-low-clamp: (w01,0);
// x-high-clamp: (0,w00)) -> bit-identical val to R11 in all cases
// (zero-weight products stay in the same summation slots).
// f1-fold retained (R10/R11-validated): n1^2 = Σr²-sum1·m1;
// dot = Σrc·val - m1·Σval with Σval = st + C·av free.
// ------------------------------------------------------------------
__global__ __launch_bounds__(256) void plane_sweep_kernel(
    const float* __restrict__ ref_feats,   // [B,C,H,W]
    const float* __restrict__ src_feats,   // [S,B,C,H,W]
    const float* __restrict__ depths,      // [D]
    const double* __restrict__ mats,       // [SB][12]
    float* __restrict__ out)               // [B,D,H,W]
{
    const int pix = blockIdx.x * 256 + threadIdx.x;   // HW = 120*256 exact
    const int by  = blockIdx.y;                       // b*D + d (scalar)
    const int d   = by % D;                           // scalar
    const int b   = by / D;                           // scalar

    const int w = pix % W;
    const int h = pix / W;

    // ---- ref stats WITHOUT storing f1: m1, n1 in one pass ----
    const float* rb = ref_feats + (size_t)b * C * HW;
    float sum1 = 0.0f, sqr1 = 0.0f;
    #pragma unroll
    for (int c = 0; c < C; ++c) {
        const float rc = rb[c * HW + pix];
        sum1 += rc;
        sqr1 = fmaf(rc, rc, sqr1);
    }
    const float m1 = sum1 * (1.0f / C);
    float sq1 = fmaf(-sum1, m1, sqr1);     // Σ(r-m1)² = Σr² - sum1·m1
    sq1 = fmaxf(sq1, 0.0f);
    const float n1 = sqrtf(sq1);

    const double u = (double)w, v = (double)h;
    const double depth = (double)depths[d];    // scalar load
    float cost = 0.0f;

    #pragma unroll 1   // one source's f64 state live at a time; s uniform
    for (int s = 0; s < S; ++s) {
        const double* Aq = mats + (s * B + b) * 12;   // scalar loads
        const double rx = fma(u, Aq[0], fma(v, Aq[1], Aq[2]));
        const double ry = fma(u, Aq[3], fma(v, Aq[4], Aq[5]));
        const double rz = fma(u, Aq[6], fma(v, Aq[7], Aq[8]));

        const double p0 = fma(depth, rx, Aq[9]);
        const double p1 = fma(depth, ry, Aq[10]);
        const double p2 = fma(depth, rz, Aq[11]);

        const bool valid = p2 > 0.001;
        const double zs = fmax(p2, 0.001);
        // f64 reciprocal: v_rcp_f64 approx + 1 Newton step (>=2^-28 rel)
#if __has_builtin(__builtin_amdgcn_rcp)
        double r = __builtin_amdgcn_rcp(zs);
#else
        double r = (double)__builtin_amdgcn_rcpf((float)zs);
        r = r * fma(-zs, r, 2.0);
#endif
        r = r * fma(-zs, r, 2.0);
        const double x = p0 * r;
        const double y = p1 * r;

        const double x0f = floor(x);
        const double y0f = floor(y);
        // sub-pixel fractions -> f32 (f64 x,y already ~1e-12-accurate)
        const float fx = (float)(x - x0f);
        const float fy = (float)(y - y0f);
        const int x0 = (int)x0f;
        const int y0 = (int)y0f;
        const int x1 = x0 + 1;
        const int y1 = y0 + 1;

        const float gx = 1.0f - fx, gy = 1.0f - fy;
        const bool okx0 = (x0 >= 0) & (x0 < W);
        const bool okx1 = (x1 >= 0) & (x1 < W);
        const bool oky0 = (y0 >= 0) & (y0 < H);
        const bool oky1 = (y1 >= 0) & (y1 < H);
        const float w00 = (valid & okx0 & oky0) ? gx * gy : 0.0f;
        const float w01 = (valid & okx1 & oky0) ? fx * gy : 0.0f;
        const float w10 = (valid & okx0 & oky1) ? gx * fy : 0.0f;
        const float w11 = (valid & okx1 & oky1) ? fx * fy : 0.0f;

        // ---- x-pair remap: one dwordx2 per row instead of two dwords.
        // xp in [0, W-2] -> pair load never leaves the row (no OOB).
        // interior: (wA,wB)=(w00,w01). x0<0 (low clamp): needed value
        // v(0) sits in pair.x -> (w01, 0). x0>=W-1 (high clamp): v(W-1)
        // sits in pair.y -> (0, w00). Zero-weight products keep their
        // original summation slots -> bit-identical val.
        const int xp = min(max(x0, 0), W - 2);
        const bool xin = (x0 == xp);
        const bool xlo = (x0 < 0);
        const float wA0 = xin ? w00 : (xlo ? w01 : 0.0f);
        const float wB0 = xin ? w01 : (xlo ? 0.0f : w00);
        const float wA1 = xin ? w10 : (xlo ? w11 : 0.0f);
        const float wB1 = xin ? w11 : (xlo ? 0.0f : w10);

        const int y0c = min(max(y0, 0), H - 1);
        const int y1c = min(max(y1, 0), H - 1);
        const int offT = y0c * W + xp;
        const int offB = y1c * W + xp;

        // sb wave-uniform -> saddr loads; channel walks in SALU
        const float* sb = src_feats + (size_t)(s * B + b) * C * HW;

        // ---- fused pass: bilinear + shifted-variance stats + rdot ----
        // c = 0 peeled (compile-time shift init).
        float rdot, st = 0.0f, s2 = 0.0f, av;
        {
            const float rc = rb[pix];
            const v2f tp = *(const v2f*)(sb + offT);
            const v2f bp = *(const v2f*)(sb + offB);
            const float val = wA0 * tp.x + wB0 * tp.y
                            + wA1 * bp.x + wB1 * bp.y;
            av = val;
            rdot = rc * val;
        }
        #pragma unroll   // FULL unroll: one contiguous load window per s
        for (int c = 1; c < C; ++c) {
            const float* p = sb + c * HW;
            const float rc = rb[c * HW + pix];
            const v2f tp = *(const v2f*)(p + offT);
            const v2f bp = *(const v2f*)(p + offB);
            const float val = wA0 * tp.x + wB0 * tp.y
                            + wA1 * bp.x + wB1 * bp.y;
            const float t = val - av;
            st += t;
            s2 = fmaf(t, t, s2);
            rdot = fmaf(rc, val, rdot);
        }
        // Σval = st + C·av ; dot = Σrc·val - m1·Σval ;
        // Σ(f2-m2)² = s2 - st²/C (shifted form; clamp rounding negatives)
        const float sv = fmaf((float)C, av, st);
        const float dot = fmaf(-m1, sv, rdot);
        float sq2 = fmaf(-st * (1.0f / C), st, s2);
        sq2 = fmaxf(sq2, 0.0f);
        cost += dot / (n1 * sqrtf(sq2) + 1e-6f);
    }

    // out base wave-uniform -> saddr store with voffset pix*4
    out[(size_t)by * HW + pix] = cost * (1.0f / S);
}

extern "C" void kernel_launch(void* const* d_in, const int* in_sizes, int n_in,
                              void* d_out, int out_size, void* d_ws, size_t ws_size,
                              hipStream_t stream) {
    const float* ref_feats  = (const float*)d_in[0];
    const float* src_feats  = (const float*)d_in[1];
    const float* ref_intr   = (const float*)d_in[2];
    const float* src_intr   = (const float*)d_in[3];
    const float* ref_to_src = (const float*)d_in[4];
    const float* depths     = (const float*)d_in[5];
    float* out = (float*)d_out;
    double* mats = (double*)d_ws;   // needs SB*12*8 = 576 bytes

    precompute_mats<<<1, 64, 0, stream>>>(ref_intr, src_intr, ref_to_src, mats);

    dim3 grid(HW / 256, B * D);     // 120 x 96, exact
    plane_sweep_kernel<<<grid, dim3(256), 0, stream>>>(
        ref_feats, src_feats, depths, mats, out);
}